// Round 5
// baseline (876.991 us; speedup 1.0000x reference)
//
#include <hip/hip_runtime.h>
#include <hip/hip_bf16.h>
#include <hip/hip_fp16.h>

typedef _Float16 v2h __attribute__((ext_vector_type(2)));
typedef _Float16 v8h __attribute__((ext_vector_type(8)));
typedef __fp16  v2hf __attribute__((ext_vector_type(2)));
typedef float v4f __attribute__((ext_vector_type(4)));

static inline __device__ float leaky(float v) { return v >= 0.f ? v : 0.01f * v; }

static inline __device__ v2h pkrtz(float a, float b) {
    v2hf r = __builtin_amdgcn_cvt_pkrtz(a, b);
    return __builtin_bit_cast(v2h, r);
}

#if __has_builtin(__builtin_amdgcn_fdot2)
static inline __device__ float fdot2(v2h a, v2h b, float c) {
    return __builtin_amdgcn_fdot2(a, b, c, false);
}
#else
static inline __device__ float fdot2(v2h a, v2h b, float c) {
    return c + (float)a[0] * (float)b[0] + (float)a[1] * (float)b[1];
}
#endif

// ---------------- workspace layout ----------------
// f32 region (element offsets from ws):
#define W4T_OFF   0          // 82944
#define H3P_OFF   82944      // 8 * 196608 = 1572864
#define H3_OFF    1655808    // 196608
#define FEAT_OFF  1852416    // 32768
#define M_OFF     1885184    // 65536
#define OT_OFF    1950720    // 4096
// f16 region starts at f32 offset 1954816 (byte 7819264):
#define F16_BASE  1954816
#define WL1_OFF   0          // 3456   conv1 weights [kz6][ky6][kxp3][oc16][2]
#define BF2_OFF   3456       // 76800  conv2 B-frags [nt2][kstep75][lane64][8]
#define BF3_OFF   80256      // 192000 conv3 B-frags [nt3][tap125][lane64][8]
#define H2C_OFF   272256     // 5619712 h2 channels-last [m175616][oc32]
#define H1C_OFF   5891968    // NB*1362944 + pad

// ---------------- weight prep ----------------
__global__ void prep_kernel(const float* __restrict__ w1, const float* __restrict__ w2,
                            const float* __restrict__ w3, const float* __restrict__ w4,
                            float* __restrict__ w4t, _Float16* __restrict__ wl1,
                            _Float16* __restrict__ Bf2, _Float16* __restrict__ Bf3) {
    int i = blockIdx.x * 256 + threadIdx.x;
    if (i < 3456) {
        int s = i & 1, oc = (i >> 1) & 15, kk = i >> 5;
        int kxp = kk % 3, ky = (kk / 3) % 6, kz = kk / 18;
        wl1[i] = (_Float16)w1[oc * 216 + kz * 36 + ky * 6 + kxp * 2 + s];
    } else if (i < 3456 + 76800) {
        int j2 = i - 3456;
        int nt = j2 / 38400, r = j2 % 38400;
        int t = r / 512, l = (r % 512) >> 3, j = r & 7;
        int oc = nt * 16 + (l & 15);
        int k = (l >> 4) * 8 + j;
        int kz = t / 15, ky = (t % 15) / 3, kxp = t % 3;
        int kx = kxp * 2 + (k >= 16 ? 1 : 0);
        int ic = k & 15;
        Bf2[j2] = (kx < 5) ? (_Float16)w2[oc * 2000 + ic * 125 + kz * 25 + ky * 5 + kx]
                           : (_Float16)0.f;
    } else if (i < 3456 + 76800 + 192000) {
        int j3 = i - (3456 + 76800);
        int nt = j3 / 64000, r = j3 % 64000;
        int tap = r / 512, l = (r % 512) >> 3, j = r & 7;
        int oc = nt * 16 + (l & 15);
        int ic = (l >> 4) * 8 + j;
        Bf3[j3] = (_Float16)w3[oc * 4000 + ic * 125 + tap];
    } else {
        int j4 = i - (3456 + 76800 + 192000);
        if (j4 < 82944) {
            int oc = j4 & 63, t = j4 >> 6;
            w4t[j4] = w4[oc * 1296 + t];
        }
    }
}

// ---------------- conv1: f16 dot2, writes h1 channels-last f16 ----------------
// x[64,92^3] f32 -> h1c[nb][z44][y44][x44][oc16] f16, k=6, s=2
// thread: 4 z x 16 oc. (256,4): 128-VGPR cap keeps the 64 accumulators in
// VGPRs — without it the compiler targets 8 waves/SIMD and round-trips every
// accumulator through AGPRs (v_accvgpr_read/write per fdot2, 2.7x VALU issue).
__global__ __launch_bounds__(256, 4) void conv1_kernel(
    const float* __restrict__ x, const _Float16* __restrict__ wl1g,
    const float* __restrict__ b1, _Float16* __restrict__ h1c, int n0, int nth) {
    __shared__ __align__(16) _Float16 wl[3456];
    int tid = threadIdx.x;
    {
        const v8h* src = (const v8h*)wl1g;
        v8h* dst = (v8h*)wl;
        for (int i2 = tid; i2 < 432; i2 += 256) dst[i2] = src[i2];
    }
    __syncthreads();

    long o = (long)blockIdx.x * 256 + tid;
    if (o >= nth) return;
    int xo = (int)(o % 44); o /= 44;
    int yo = (int)(o % 44); o /= 44;
    int zq = (int)(o % 11);
    int nb = (int)(o / 11);

    const float* xin = x + (long)(n0 + nb) * 778688;
    float acc[4][16];
#pragma unroll
    for (int j = 0; j < 4; j++)
#pragma unroll
        for (int q = 0; q < 16; q++) acc[j][q] = 0.f;

    int z0 = zq * 4;
    int izb = 2 * z0, iyb = 2 * yo, ixb = 2 * xo;

    for (int kz = 0; kz < 6; kz++) {
        for (int ky = 0; ky < 6; ky++) {
            const float* xr = xin + (long)(izb + kz) * 8464 + (iyb + ky) * 92 + ixb;
            v2h v[4][3];
#pragma unroll
            for (int j = 0; j < 4; j++) {
                const float2* p = (const float2*)(xr + j * 2 * 8464);
                float2 a = p[0], b = p[1], c = p[2];
                v[j][0] = pkrtz(a.x, a.y);
                v[j][1] = pkrtz(b.x, b.y);
                v[j][2] = pkrtz(c.x, c.y);
            }
            const _Float16* wb = wl + (kz * 6 + ky) * 96;
#pragma unroll
            for (int kxp = 0; kxp < 3; kxp++) {
#pragma unroll
                for (int q = 0; q < 4; q++) {
                    v8h wv = *(const v8h*)(wb + kxp * 32 + q * 8);
                    v2h w0 = {wv[0], wv[1]}, w1_ = {wv[2], wv[3]};
                    v2h w2_ = {wv[4], wv[5]}, w3_ = {wv[6], wv[7]};
#pragma unroll
                    for (int j = 0; j < 4; j++) {
                        acc[j][q*4+0] = fdot2(v[j][kxp], w0,  acc[j][q*4+0]);
                        acc[j][q*4+1] = fdot2(v[j][kxp], w1_, acc[j][q*4+1]);
                        acc[j][q*4+2] = fdot2(v[j][kxp], w2_, acc[j][q*4+2]);
                        acc[j][q*4+3] = fdot2(v[j][kxp], w3_, acc[j][q*4+3]);
                    }
                }
            }
        }
    }

#pragma unroll
    for (int j = 0; j < 4; j++) {
        union { v2h h2[8]; uint4 u4[2]; } u;
#pragma unroll
        for (int p = 0; p < 8; p++) {
            float e0 = leaky(acc[j][2*p]   + b1[2*p]);
            float e1 = leaky(acc[j][2*p+1] + b1[2*p+1]);
            u.h2[p] = pkrtz(e0, e1);
        }
        _Float16* dst = h1c + ((long)((nb * 44 + z0 + j) * 44 + yo) * 44 + xo) * 16;
        *(uint4*)dst = u.u4[0];
        *((uint4*)dst + 1) = u.u4[1];
    }
}

// ---------------- conv2: MFMA implicit GEMM, B staged in LDS ----------------
// h1c[nb][iz][iy][ix][ic16] f16 -> h2c[m][oc32] f16, k=5, s=3
// wave: 2 M-tiles (16 pos each) x 32 oc; K = 150 padded taps x 16 ic, 75 ksteps
// B-frags (150 KB total, > L1) staged in LDS in 3 chunks of 25 ksteps (50 KB)
__global__ __launch_bounds__(256) void conv2_kernel(
    const _Float16* __restrict__ h1c, const _Float16* __restrict__ Bf2,
    const float* __restrict__ b2, _Float16* __restrict__ h2c, int n0, int mlimit) {
    __shared__ __align__(16) _Float16 Bl[25 * 1024];  // 50 KB
    int tid = threadIdx.x;
    int lane = tid & 63, wv = tid >> 6;
    int t0 = (blockIdx.x * 4 + wv) * 2;
    int col = lane & 15, kgrp = lane >> 4;
    int par = kgrp >> 1, ico = (kgrp & 1) * 8;

    int base[2];
    bool valid[2];
#pragma unroll
    for (int i = 0; i < 2; i++) {
        int m = (t0 + i) * 16 + col;
        valid[i] = m < mlimit;
        int mm = valid[i] ? m : 0;
        int nl = mm / 2744, r = mm % 2744;
        int z = r / 196; r %= 196;
        int y = r / 14, xx = r % 14;
        base[i] = nl * 1362944 + z * 3 * 30976 + y * 3 * 704 + xx * 3 * 16 + ico + par * 16;
    }

    v4f acc[2][2];
#pragma unroll
    for (int i = 0; i < 2; i++)
#pragma unroll
        for (int nt = 0; nt < 2; nt++) acc[i][nt] = (v4f){0.f, 0.f, 0.f, 0.f};

    for (int c = 0; c < 3; c++) {
        __syncthreads();
        // stage ksteps [c*25, c*25+25) for both n-tiles: 3200 v8h
        {
            const v8h* s0 = (const v8h*)(Bf2 + (c * 25) * 512);        // nt=0
            const v8h* s1 = (const v8h*)(Bf2 + (75 + c * 25) * 512);   // nt=1
            v8h* dl = (v8h*)Bl;
            for (int i2 = tid; i2 < 3200; i2 += 256) {
                int tl = i2 >> 7, rem = i2 & 127;
                int nt = rem >> 6, l8 = rem & 63;
                dl[tl * 128 + nt * 64 + l8] = nt ? s1[tl * 64 + l8] : s0[tl * 64 + l8];
            }
        }
        __syncthreads();
#pragma unroll 5
        for (int tl = 0; tl < 25; tl++) {
            int t = c * 25 + tl;
            int kz = t / 15, rr = t % 15;
            int ky = rr / 3, kxp = rr % 3;
            int d = kz * 30976 + ky * 704 + kxp * 32;
            v8h A0 = *(const v8h*)(h1c + base[0] + d);
            v8h A1 = *(const v8h*)(h1c + base[1] + d);
            v8h B0 = *(const v8h*)(Bl + tl * 1024 + lane * 8);
            v8h B1 = *(const v8h*)(Bl + tl * 1024 + 512 + lane * 8);
            acc[0][0] = __builtin_amdgcn_mfma_f32_16x16x32_f16(A0, B0, acc[0][0], 0, 0, 0);
            acc[0][1] = __builtin_amdgcn_mfma_f32_16x16x32_f16(A0, B1, acc[0][1], 0, 0, 0);
            acc[1][0] = __builtin_amdgcn_mfma_f32_16x16x32_f16(A1, B0, acc[1][0], 0, 0, 0);
            acc[1][1] = __builtin_amdgcn_mfma_f32_16x16x32_f16(A1, B1, acc[1][1], 0, 0, 0);
        }
    }

#pragma unroll
    for (int i = 0; i < 2; i++) {
        if (!valid[i]) continue;
#pragma unroll
        for (int nt = 0; nt < 2; nt++) {
            int oc = nt * 16 + col;
            float bb = b2[oc];
#pragma unroll
            for (int reg = 0; reg < 4; reg++) {
                int mlocal = (t0 + i) * 16 + kgrp * 4 + reg;
                float vv = leaky(acc[i][nt][reg] + bb);
                h2c[(long)(n0 * 2744 + mlocal) * 32 + oc] = (_Float16)vv;
            }
        }
    }
}

// ---------------- conv3: MFMA implicit GEMM, K-split x8 ----------------
// h2c[m2744n][ic32] f16 -> h3p[chunk8][m4096][oc48] f32 partials, k=5, s=3
__global__ __launch_bounds__(256) void conv3_kernel(
    const _Float16* __restrict__ h2c, const _Float16* __restrict__ Bf3,
    float* __restrict__ h3p) {
    int tid = threadIdx.x;
    int lane = tid & 63, wv = tid >> 6;
    int mt = blockIdx.x * 4 + wv;   // 0..255
    int chunk = blockIdx.y;         // 0..7
    int col = lane & 15, kgrp = lane >> 4;
    int m = mt * 16 + col;
    int n = m >> 6, pos = m & 63;
    int z = pos >> 4, y = (pos >> 2) & 3, xx = pos & 3;
    int base = (n * 2744 + z * 3 * 196 + y * 3 * 14 + xx * 3) * 32 + kgrp * 8;

    v4f acc[3];
#pragma unroll
    for (int nt = 0; nt < 3; nt++) acc[nt] = (v4f){0.f, 0.f, 0.f, 0.f};

    int tap0 = chunk * 16;
    int tap1 = tap0 + 16 < 125 ? tap0 + 16 : 125;
    for (int tap = tap0; tap < tap1; tap++) {
        int kz = tap / 25, rr = tap % 25, ky = rr / 5, kx = rr % 5;
        int d = (kz * 196 + ky * 14 + kx) * 32;
        v8h A  = *(const v8h*)(h2c + base + d);
        v8h B0 = *(const v8h*)(Bf3 + tap * 512 + lane * 8);
        v8h B1 = *(const v8h*)(Bf3 + (125 + tap) * 512 + lane * 8);
        v8h B2 = *(const v8h*)(Bf3 + (250 + tap) * 512 + lane * 8);
        acc[0] = __builtin_amdgcn_mfma_f32_16x16x32_f16(A, B0, acc[0], 0, 0, 0);
        acc[1] = __builtin_amdgcn_mfma_f32_16x16x32_f16(A, B1, acc[1], 0, 0, 0);
        acc[2] = __builtin_amdgcn_mfma_f32_16x16x32_f16(A, B2, acc[2], 0, 0, 0);
    }

    float* outp = h3p + (long)chunk * 196608;
#pragma unroll
    for (int nt = 0; nt < 3; nt++)
#pragma unroll
        for (int reg = 0; reg < 4; reg++) {
            int md = mt * 16 + kgrp * 4 + reg;
            outp[md * 48 + nt * 16 + col] = acc[nt][reg];
        }
}

// h3[n][oc48][pos64] = leaky(sum of 8 partials + b3)
__global__ void combine3(float* __restrict__ h3, const float* __restrict__ h3p,
                         const float* __restrict__ b3) {
    int i = blockIdx.x * 256 + threadIdx.x;  // 196608 = 768*256
    int m = i / 48, oc = i % 48;
    float v = b3[oc];
#pragma unroll
    for (int p = 0; p < 8; p++) v += h3p[i + p * 196608];
    h3[((m >> 6) * 48 + oc) * 64 + (m & 63)] = leaky(v);
}

// conv4: h3[64,48,4,4,4] f32 -> feat[64,512], k=3, s=1
__global__ void conv4_kernel(const float* __restrict__ h3, const float* __restrict__ w4t,
                             const float* __restrict__ b4, float* __restrict__ feat) {
    int o = blockIdx.x * 256 + threadIdx.x;  // 32768 = 128*256
    int pos = o & 7;
    int oc  = (o >> 3) & 63;
    int n   = o >> 9;
    int px = pos & 1, py = (pos >> 1) & 1, pz = pos >> 2;
    const float* xn = h3 + (long)n * 48 * 64;
    float acc = 0.f;
    for (int ic = 0; ic < 48; ic++) {
        const float* xc = xn + ic * 64;
        int tb = ic * 27;
#pragma unroll
        for (int kz = 0; kz < 3; kz++)
#pragma unroll
            for (int ky = 0; ky < 3; ky++)
#pragma unroll
                for (int kx = 0; kx < 3; kx++) {
                    float v = xc[(pz + kz) * 16 + (py + ky) * 4 + (px + kx)];
                    acc += v * w4t[(tb + (kz * 3 + ky) * 3 + kx) * 64 + oc];
                }
    }
    feat[o] = leaky(acc + b4[oc]);  // o == n*512 + oc*8 + pos
}

// M[64,1024] = feat[64,512] @ T[512,1024]
__global__ void m_kernel(const float* __restrict__ feat, const float* __restrict__ T,
                         float* __restrict__ M) {
    int o = blockIdx.x * 256 + threadIdx.x;  // 65536 = 256*256
    int col = o & 1023;
    int n   = o >> 10;
    const float* fr = feat + n * 512;
    float acc = 0.f;
#pragma unroll 4
    for (int f = 0; f < 512; f++) acc += fr[f] * T[f * 1024 + col];
    M[o] = acc;
}

// out_T[i,k] = sum_j exp( sum_l |M[i,k,l]-M[j,k,l]| )
__global__ void outt_kernel(const float* __restrict__ M, float* __restrict__ oT) {
    int o = blockIdx.x * 256 + threadIdx.x;  // 4096 = 16*256
    int k = o & 63;
    int i = o >> 6;
    float mi[16];
    const float4* Mi = (const float4*)(M + i * 1024 + k * 16);
#pragma unroll
    for (int q = 0; q < 4; q++) {
        float4 a = Mi[q];
        mi[q*4+0] = a.x; mi[q*4+1] = a.y; mi[q*4+2] = a.z; mi[q*4+3] = a.w;
    }
    float s = 0.f;
    for (int j = 0; j < 64; j++) {
        const float4* Mj = (const float4*)(M + j * 1024 + k * 16);
        float d = 0.f;
#pragma unroll
        for (int q = 0; q < 4; q++) {
            float4 a = Mj[q];
            d += fabsf(mi[q*4+0]-a.x) + fabsf(mi[q*4+1]-a.y) + fabsf(mi[q*4+2]-a.z) + fabsf(mi[q*4+3]-a.w);
        }
        s += __expf(d);
    }
    oT[o] = s;
}

// out[i] = sigmoid( feat[i,:].Wm[0:512] + oT[i,:].Wm[512:576] + bm )
__global__ void final_kernel(const float* __restrict__ feat, const float* __restrict__ oT,
                             const float* __restrict__ Wm, const float* __restrict__ bm,
                             float* __restrict__ out) {
    int i = blockIdx.x;      // 64 outputs
    int lane = threadIdx.x;  // 64 lanes
    const float* fr = feat + i * 512;
    float z = 0.f;
#pragma unroll
    for (int q = 0; q < 8; q++) z += fr[lane + q * 64] * Wm[lane + q * 64];
    z += oT[i * 64 + lane] * Wm[512 + lane];
#pragma unroll
    for (int off = 32; off > 0; off >>= 1) z += __shfl_down(z, off);
    if (lane == 0) out[i] = 1.f / (1.f + __expf(-(z + bm[0])));
}

extern "C" void kernel_launch(void* const* d_in, const int* in_sizes, int n_in,
                              void* d_out, int out_size, void* d_ws, size_t ws_size,
                              hipStream_t stream) {
    const float* x  = (const float*)d_in[0];
    const float* w1 = (const float*)d_in[1];
    const float* b1 = (const float*)d_in[2];
    const float* w2 = (const float*)d_in[3];
    const float* b2 = (const float*)d_in[4];
    const float* w3 = (const float*)d_in[5];
    const float* b3 = (const float*)d_in[6];
    const float* w4 = (const float*)d_in[7];
    const float* b4 = (const float*)d_in[8];
    const float* T  = (const float*)d_in[9];
    const float* Wm = (const float*)d_in[10];
    const float* bm = (const float*)d_in[11];

    float* ws   = (float*)d_ws;
    float* w4t  = ws + W4T_OFF;
    float* h3p  = ws + H3P_OFF;
    float* h3   = ws + H3_OFF;
    float* feat = ws + FEAT_OFF;
    float* Mb   = ws + M_OFF;
    float* oT   = ws + OT_OFF;
    _Float16* f16b = (_Float16*)(ws + F16_BASE);
    _Float16* wl1  = f16b + WL1_OFF;
    _Float16* Bf2  = f16b + BF2_OFF;
    _Float16* Bf3  = f16b + BF3_OFF;
    _Float16* h2c  = f16b + H2C_OFF;
    _Float16* h1c  = f16b + H1C_OFF;

    prep_kernel<<<1388, 256, 0, stream>>>(w1, w2, w3, w4, w4t, wl1, Bf2, Bf3);

    // choose batch-group size by workspace capacity
    size_t fixed_bytes = (size_t)F16_BASE * 4 + (size_t)H1C_OFF * 2;
    int NB;
    if (ws_size >= fixed_bytes + (64ll * 1362944 + 64) * 2) NB = 64;
    else if (ws_size >= fixed_bytes + (16ll * 1362944 + 64) * 2) NB = 16;
    else NB = 8;

    for (int n0 = 0; n0 < 64; n0 += NB) {
        int nth = NB * 21296;
        conv1_kernel<<<(nth + 255) / 256, 256, 0, stream>>>(x, wl1, b1, h1c, n0, nth);
        int mlimit = NB * 2744;
        int blocks2 = (mlimit + 127) / 128;  // 2 tiles x 16 pos x 4 waves
        conv2_kernel<<<blocks2, 256, 0, stream>>>(h1c, Bf2, b2, h2c, n0, mlimit);
    }
    conv3_kernel<<<dim3(64, 8), 256, 0, stream>>>(h2c, Bf3, h3p);
    combine3<<<768, 256, 0, stream>>>(h3, h3p, b3);
    conv4_kernel<<<128, 256, 0, stream>>>(h3, w4t, b4, feat);
    m_kernel<<<256, 256, 0, stream>>>(feat, T, Mb);
    outt_kernel<<<16, 256, 0, stream>>>(Mb, oT);
    final_kernel<<<64, 64, 0, stream>>>(feat, oT, Wm, bm, (float*)d_out);
}